// Round 1
// baseline (295.918 us; speedup 1.0000x reference)
//
#include <hip/hip_runtime.h>
#include <hip/hip_bf16.h>

// GraphAttentionEncoder: 2x GATConv (shared edges) + gated mix + residual + LN
// N=50000, DIM=128, H=4, C=32, E=800000 (+N self loops)
//
// R7 changes vs R6:
//  - w[] (per-edge exp weights, 12.8MB) is no longer materialized. k_agg
//    recomputes w = exp(lrelu(es[src]+ed[dst])) in-register from a single
//    float2 gather of es (1.6MB, L2-resident). Kills k_fill's 64B/edge
//    random es/ed gathers, its exp VALU, and the 16B/edge random scatter.
//  - es/ed layout interleaved to [node][head][layer] so the per-edge src
//    logit load is one float2.
//  - k_lb's logits phase moved into k_fill's grid (es/ed are now only
//    needed by k_agg, so they can be produced concurrently with the sort).
//    A tiny k_sb kernel computes bsum for the scan.
//  - k_agg inner loop keeps the R3-proven x4 unroll structure.

typedef unsigned short u16;
typedef __bf16 bf16x8 __attribute__((ext_vector_type(8)));
typedef float f32x4 __attribute__((ext_vector_type(4)));

#define LRELU_SLOPE 0.2f
#define LN_EPS 1e-5f
#define SH 8                 // atomic shards

__device__ __forceinline__ float bfbits(unsigned int hi_bits) {
    union { unsigned int i; float f; } v; v.i = hi_bits; return v.f;
}
__device__ __forceinline__ float bflo(unsigned int u) { return bfbits(u << 16); }
__device__ __forceinline__ float bfhi(unsigned int u) { return bfbits(u & 0xFFFF0000u); }
__device__ __forceinline__ u16 f2bf(float f) {
    union { float f; unsigned int i; } v; v.f = f;
    unsigned int lsb = (v.i >> 16) & 1u;
    v.i += 0x7FFFu + lsb;                 // round-to-nearest-even
    return (u16)(v.i >> 16);
}

// wb[col][k] = W[k][col] bf16 (col 0-127 -> W1, 128-255 -> W2); deg8 = 0
__global__ void k_prep(const float* __restrict__ W1, const float* __restrict__ W2,
                       u16* __restrict__ wb, int* __restrict__ deg8, int n) {
    int i = blockIdx.x * 256 + threadIdx.x;
    if (i < 32768) {
        int col = i >> 7, k = i & 127;
        float v = (col < 128) ? W1[k * 128 + col] : W2[k * 128 + (col - 128)];
        wb[i] = f2bf(v);
    }
    if (i < n) {
#pragma unroll
        for (int x = 0; x < SH; x++) deg8[x * n + i] = 0;
    }
}

// K2: blocks [0,Gg) = MFMA GEMM, blocks [Gg,Gg+Gc) = degree count.
// GEMM output packed: hbp[row][c] = (h2[c]<<16)|h1[c], c in [0,128)
__global__ __launch_bounds__(256) void k_cg(const float* __restrict__ x,
                                            const u16* __restrict__ wb,
                                            unsigned int* __restrict__ hbp, int n,
                                            const int* __restrict__ ei,
                                            int* __restrict__ deg8, int E, int Gg) {
    if ((int)blockIdx.x >= Gg) {
        int i = ((int)blockIdx.x - Gg) * 256 + threadIdx.x;
        if (i < E) {
            int sh = (i >> 8) & (SH - 1);
            atomicAdd(&deg8[sh * n + ei[E + i]], 1);
        }
        return;
    }
    int wave = threadIdx.x >> 6, lane = threadIdx.x & 63;
    int quad = lane >> 4, r16 = lane & 15;
    int row = blockIdx.x * 64 + wave * 16 + r16;
    int arow = (row < n) ? row : n - 1;
    const float* xp = x + (size_t)arow * 128 + quad * 8;
    union { u16 u[8]; bf16x8 b; } ar;
    bf16x8 a[4];
#pragma unroll
    for (int ks = 0; ks < 4; ks++) {
        float4 lo = *(const float4*)(xp + ks * 32);
        float4 hi = *(const float4*)(xp + ks * 32 + 4);
        ar.u[0] = f2bf(lo.x); ar.u[1] = f2bf(lo.y); ar.u[2] = f2bf(lo.z); ar.u[3] = f2bf(lo.w);
        ar.u[4] = f2bf(hi.x); ar.u[5] = f2bf(hi.y); ar.u[6] = f2bf(hi.z); ar.u[7] = f2bf(hi.w);
        a[ks] = ar.b;
    }
    f32x4 acc[16];
#pragma unroll
    for (int t = 0; t < 16; t++) acc[t] = (f32x4){0.f, 0.f, 0.f, 0.f};
    const u16* bbase = wb + r16 * 128 + quad * 8;
#pragma unroll
    for (int t = 0; t < 16; t++) {
        const u16* bp = bbase + t * 2048;      // t*16 rows * 128
#pragma unroll
        for (int ks = 0; ks < 4; ks++) {
            bf16x8 b = *(const bf16x8*)(bp + ks * 32);
            acc[t] = __builtin_amdgcn_mfma_f32_16x16x32_bf16(a[ks], b, acc[t], 0, 0, 0);
        }
    }
    int row0 = blockIdx.x * 64 + wave * 16 + quad * 4;
#pragma unroll
    for (int t = 0; t < 8; t++) {
        int c = t * 16 + r16;                  // packed col 0..127
#pragma unroll
        for (int g = 0; g < 4; g++) {
            int gr = row0 + g;
            if (gr < n) {
                unsigned int pv = ((unsigned int)f2bf(acc[t + 8][g]) << 16) | f2bf(acc[t][g]);
                hbp[(size_t)gr * 128 + c] = pv;
            }
        }
    }
}

// bsum[b] = total degree of nodes in block b (input to k_scan phase 1)
__global__ void k_sb(const int* __restrict__ deg8, int* __restrict__ bsum, int n) {
    __shared__ int s[256];
    int i = blockIdx.x * 256 + threadIdx.x;
    int v = 0;
    if (i < n) {
#pragma unroll
        for (int x = 0; x < SH; x++) v += deg8[x * n + i];
    }
    s[threadIdx.x] = v;
    __syncthreads();
    for (int o = 128; o; o >>= 1) {
        if (threadIdx.x < o) s[threadIdx.x] += s[threadIdx.x + o];
        __syncthreads();
    }
    if (threadIdx.x == 0) bsum[blockIdx.x] = s[0];
}

// scan -> offs; deg8 converted IN-PLACE to per-shard cursors:
// cursor[x][i] = offs[i] + sum_{y<x} deg[y][i]
__global__ void k_scan(int* __restrict__ deg8, const int* __restrict__ bsum,
                       int* __restrict__ offs, int nb, int n) {
    __shared__ int s[256];
    __shared__ int bp;
    int t = threadIdx.x;
    int bv = (t < nb) ? bsum[t] : 0;
    s[t] = bv;
    __syncthreads();
    for (int o = 1; o < 256; o <<= 1) {
        int u = (t >= o) ? s[t - o] : 0;
        __syncthreads();
        s[t] += u;
        __syncthreads();
    }
    if (t == (int)blockIdx.x) bp = s[t] - bv;   // exclusive prefix of this block
    __syncthreads();
    int i = blockIdx.x * 256 + t;
    int d[SH];
    int v = 0;
    if (i < n) {
#pragma unroll
        for (int x = 0; x < SH; x++) { d[x] = deg8[x * n + i]; v += d[x]; }
    }
    s[t] = v;
    __syncthreads();
    for (int o = 1; o < 256; o <<= 1) {
        int u = (t >= o) ? s[t - o] : 0;
        __syncthreads();
        s[t] += u;
        __syncthreads();
    }
    if (i < n) {
        int e = bp + s[t] - v;
        offs[i] = e;
        int run = e;
#pragma unroll
        for (int x = 0; x < SH; x++) { deg8[x * n + i] = run; run += d[x]; }
        if (i == n - 1) offs[n] = e + v;
    }
}

// K5: blocks [0,Gc) = counting sort (ssrc only), blocks [Gc,Gc+Gl) = per-
// (node,head) logits. es/ed rows: [node][head][layer] (slot = head*2+layer)
__global__ void k_fl(const int* __restrict__ ei, int* __restrict__ cursor8,
                     int* __restrict__ ssrc, int E, int n,
                     const unsigned int* __restrict__ hbp,
                     const float* __restrict__ as1, const float* __restrict__ ad1,
                     const float* __restrict__ as2, const float* __restrict__ ad2,
                     float* __restrict__ es, float* __restrict__ ed, int Gc) {
    if ((int)blockIdx.x >= Gc) {
        int i = ((int)blockIdx.x - Gc) * 256 + threadIdx.x;
        if (i >= n * 4) return;
        int node = i >> 2, head = i & 3;
        const uint4* hv = (const uint4*)(hbp + (size_t)node * 128 + head * 32);
        const float* a1 = as1 + head * 32;
        const float* d1 = ad1 + head * 32;
        const float* a2 = as2 + head * 32;
        const float* d2 = ad2 + head * 32;
        float s1 = 0.f, t1 = 0.f, s2 = 0.f, t2 = 0.f;
#pragma unroll
        for (int q = 0; q < 8; q++) {
            uint4 w = hv[q];
            unsigned int ws[4] = {w.x, w.y, w.z, w.w};
#pragma unroll
            for (int h = 0; h < 4; h++) {
                int c = q * 4 + h;
                float v1 = bflo(ws[h]), v2 = bfhi(ws[h]);
                s1 += v1 * a1[c]; t1 += v1 * d1[c];
                s2 += v2 * a2[c]; t2 += v2 * d2[c];
            }
        }
        *(float2*)(es + node * 8 + head * 2) = make_float2(s1, s2);
        *(float2*)(ed + node * 8 + head * 2) = make_float2(t1, t2);
        return;
    }
    int i = blockIdx.x * 256 + threadIdx.x;
    if (i >= E) return;
    int s = ei[i], d = ei[E + i];
    int sh = (i >> 8) & (SH - 1);
    int pos = atomicAdd(&cursor8[sh * n + d], 1);
    ssrc[pos] = s;
}

__device__ __forceinline__ float wred(float v) {
#pragma unroll
    for (int off = 32; off; off >>= 1) v += __shfl_xor(v, off, 64);
    return v;
}

// one wave per node; lane owns packed cols ca=2*lane, cb=2*lane+1 (same head).
// Edge weights recomputed in-register: w = exp(lrelu(es[src]+ed[dst])).
__global__ __launch_bounds__(256) void k_agg(
    const int* __restrict__ offs, const int* __restrict__ ssrc,
    const unsigned int* __restrict__ hbp,
    const float* __restrict__ es, const float* __restrict__ ed,
    const float* __restrict__ b1, const float* __restrict__ b2,
    const float* __restrict__ gW, const float* __restrict__ gb,
    const float* __restrict__ x, const float* __restrict__ gamma,
    const float* __restrict__ beta, float* __restrict__ out, int n) {
    int wave = threadIdx.x >> 6, lane = threadIdx.x & 63;
    int node = blockIdx.x * 4 + wave;
    if (node >= n) return;
    node = __builtin_amdgcn_readfirstlane(node);   // wave-uniform -> s_loads

    int ca = lane * 2;
    int head = lane >> 4;                  // = ca>>5
    int hh = head * 2;                     // slot base in es/ed rows

    float2 edv = *(const float2*)(ed + node * 8 + hh);
    float ed1 = edv.x, ed2 = edv.y;        // dst logit terms, loop-invariant

    float l1 = 0.f, l2 = 0.f;
    float a1a = 0.f, a1b = 0.f, a2a = 0.f, a2b = 0.f;

#define EDGE(sv, q) { \
        float e1 = sv.x + ed1; e1 = fmaxf(e1, LRELU_SLOPE * e1); \
        float e2 = sv.y + ed2; e2 = fmaxf(e2, LRELU_SLOPE * e2); \
        float ww1 = __expf(e1), ww2 = __expf(e2); \
        l1 += ww1; l2 += ww2; \
        a1a += ww1 * bflo(q.x); a1b += ww1 * bflo(q.y); \
        a2a += ww2 * bfhi(q.x); a2b += ww2 * bfhi(q.y); }

    // self-loop (es/ed rows of this node, coalesced hbp row read)
    {
        float2 svs = *(const float2*)(es + node * 8 + hh);
        uint2 qs = *(const uint2*)(hbp + (size_t)node * 128 + ca);
        EDGE(svs, qs)
    }

    int beg = offs[node], end = offs[node + 1];
    int k = beg;
    for (; k + 3 < end; k += 4) {
        int j0 = ssrc[k], j1 = ssrc[k + 1], j2 = ssrc[k + 2], j3 = ssrc[k + 3];
        float2 s0 = *(const float2*)(es + j0 * 8 + hh);
        float2 s1 = *(const float2*)(es + j1 * 8 + hh);
        float2 s2 = *(const float2*)(es + j2 * 8 + hh);
        float2 s3 = *(const float2*)(es + j3 * 8 + hh);
        uint2 q0 = *(const uint2*)(hbp + (size_t)j0 * 128 + ca);
        uint2 q1 = *(const uint2*)(hbp + (size_t)j1 * 128 + ca);
        uint2 q2 = *(const uint2*)(hbp + (size_t)j2 * 128 + ca);
        uint2 q3 = *(const uint2*)(hbp + (size_t)j3 * 128 + ca);
        EDGE(s0, q0) EDGE(s1, q1) EDGE(s2, q2) EDGE(s3, q3)
    }
    for (; k < end; k++) {
        int j = ssrc[k];
        float2 sv = *(const float2*)(es + j * 8 + hh);
        uint2 q = *(const uint2*)(hbp + (size_t)j * 128 + ca);
        EDGE(sv, q)
    }
#undef EDGE

    float2 b1v = *(const float2*)(b1 + ca);
    float2 b2v = *(const float2*)(b2 + ca);
    float r1 = 1.f / l1, r2 = 1.f / l2;
    float o1a = a1a * r1 + b1v.x;
    float o1b = a1b * r1 + b1v.y;
    float o2a = a2a * r2 + b2v.x;
    float o2b = a2b * r2 + b2v.y;

    // gate logits: concat(out1,out2) @ gate_W(256x2) + gate_b
    int cb = ca + 1;
    float2 g1a = *(const float2*)(gW + 2 * ca);          // rows ca,cb
    float2 g1b = *(const float2*)(gW + 2 * cb);
    float2 g2a = *(const float2*)(gW + 2 * (128 + ca));
    float2 g2b = *(const float2*)(gW + 2 * (128 + cb));
    float p0 = o1a * g1a.x + o1b * g1b.x + o2a * g2a.x + o2b * g2b.x;
    float p1 = o1a * g1a.y + o1b * g1b.y + o2a * g2a.y + o2b * g2b.y;
    p0 = wred(p0) + gb[0];
    p1 = wred(p1) + gb[1];
    float mg = fmaxf(p0, p1);
    float eg0 = __expf(p0 - mg), eg1 = __expf(p1 - mg);
    float g0 = eg0 / (eg0 + eg1), g1 = 1.f - g0;

    float2 xv = *(const float2*)(x + (size_t)node * 128 + ca);
    float ya = xv.x + g0 * o1a + g1 * o2a;
    float yb = xv.y + g0 * o1b + g1 * o2b;

    float s  = wred(ya + yb);
    float ss = wred(ya * ya + yb * yb);
    float mean = s * (1.f / 128.f);
    float var  = ss * (1.f / 128.f) - mean * mean;
    float rstd = rsqrtf(var + LN_EPS);
    float2 gv = *(const float2*)(gamma + ca);
    float2 bv = *(const float2*)(beta + ca);
    float2 ov;
    ov.x = (ya - mean) * rstd * gv.x + bv.x;
    ov.y = (yb - mean) * rstd * gv.y + bv.y;
    *(float2*)(out + (size_t)node * 128 + ca) = ov;
}

extern "C" void kernel_launch(void* const* d_in, const int* in_sizes, int n_in,
                              void* d_out, int out_size, void* d_ws, size_t ws_size,
                              hipStream_t stream) {
    const float* x   = (const float*)d_in[0];
    const int*   ei  = (const int*)d_in[1];
    const float* W1  = (const float*)d_in[2];
    const float* b1  = (const float*)d_in[3];
    const float* as1 = (const float*)d_in[4];
    const float* ad1 = (const float*)d_in[5];
    const float* W2  = (const float*)d_in[6];
    const float* b2  = (const float*)d_in[7];
    const float* as2 = (const float*)d_in[8];
    const float* ad2 = (const float*)d_in[9];
    const float* gW  = (const float*)d_in[10];
    const float* gb  = (const float*)d_in[11];
    const float* gamma = (const float*)d_in[12];
    const float* beta  = (const float*)d_in[13];
    float* out = (float*)d_out;

    int n = in_sizes[0] / 128;
    int E = in_sizes[1] / 2;

    char* p = (char*)d_ws;
    auto take = [&](size_t bytes) {
        char* q = p;
        p += (bytes + 255) & ~(size_t)255;
        return (void*)q;
    };
    u16* wb    = (u16*)take((size_t)256 * 128 * 2);
    unsigned int* hbp = (unsigned int*)take((size_t)n * 128 * 4);
    float* es  = (float*)take((size_t)n * 8 * 4);
    float* ed  = (float*)take((size_t)n * 8 * 4);
    int* deg8  = (int*)take((size_t)SH * n * 4);   // becomes cursor8 after k_scan
    int* offs  = (int*)take((size_t)(n + 1) * 4);
    int* bsum  = (int*)take((size_t)256 * 4);
    int* ssrc  = (int*)take((size_t)E * 4);

    int nb = (n + 255) / 256;       // 196 (<= 256 required by k_scan)
    int Gg = (n + 63) / 64;         // gemm blocks
    int Gc = (E + 255) / 256;       // count/sort blocks
    int Gl = (n * 4 + 255) / 256;   // logits blocks

    k_prep<<<nb, 256, 0, stream>>>(W1, W2, wb, deg8, n);
    k_cg<<<Gg + Gc, 256, 0, stream>>>(x, wb, hbp, n, ei, deg8, E, Gg);
    k_sb<<<nb, 256, 0, stream>>>(deg8, bsum, n);
    k_scan<<<nb, 256, 0, stream>>>(deg8, bsum, offs, nb, n);
    k_fl<<<Gc + Gl, 256, 0, stream>>>(ei, deg8, ssrc, E, n, hbp,
                                      as1, ad1, as2, ad2, es, ed, Gc);
    k_agg<<<(n + 3) / 4, 256, 0, stream>>>(offs, ssrc, hbp, es, ed,
                                           b1, b2, gW, gb, x, gamma, beta, out, n);
}

// Round 2
// 260.539 us; speedup vs baseline: 1.1358x; 1.1358x over previous
//
#include <hip/hip_runtime.h>
#include <hip/hip_bf16.h>

// GraphAttentionEncoder: 2x GATConv (shared edges) + gated mix + residual + LN
// N=50000, DIM=128, H=4, C=32, E=800000 (+N self loops)
//
// R8 changes vs R7:
//  - The per-edge returning atomicAdd is moved OUT of k_fl into k_cg's
//    count phase (which already did the same atomic fire-and-forget).
//    The returned value is the edge's rank within its (shard,dst) slice,
//    stored coalesced to rnk[i] (3.2MB). The atomic's round-trip latency
//    is hidden by the co-resident MFMA GEMM waves.
//  - k_fl's sort phase becomes atomic-free: pos = cursor8[sh*n+d] + rnk[i]
//    (cursor8 is now read-only after k_scan, L2-resident 1.6MB). The
//    per-wave dependent chain drops from {atomic rt -> store} to
//    {L2 gather -> store}; R7's k_fl showed VALUBusy 1.5% / HBM 9.8% =
//    naked atomic-latency stall.
//  - Everything else (k_agg in-register edge weights, logits fused into
//    k_fl's grid, GEMM/count fusion) unchanged from R7.

typedef unsigned short u16;
typedef __bf16 bf16x8 __attribute__((ext_vector_type(8)));
typedef float f32x4 __attribute__((ext_vector_type(4)));

#define LRELU_SLOPE 0.2f
#define LN_EPS 1e-5f
#define SH 8                 // atomic shards

__device__ __forceinline__ float bfbits(unsigned int hi_bits) {
    union { unsigned int i; float f; } v; v.i = hi_bits; return v.f;
}
__device__ __forceinline__ float bflo(unsigned int u) { return bfbits(u << 16); }
__device__ __forceinline__ float bfhi(unsigned int u) { return bfbits(u & 0xFFFF0000u); }
__device__ __forceinline__ u16 f2bf(float f) {
    union { float f; unsigned int i; } v; v.f = f;
    unsigned int lsb = (v.i >> 16) & 1u;
    v.i += 0x7FFFu + lsb;                 // round-to-nearest-even
    return (u16)(v.i >> 16);
}

// wb[col][k] = W[k][col] bf16 (col 0-127 -> W1, 128-255 -> W2); deg8 = 0
__global__ void k_prep(const float* __restrict__ W1, const float* __restrict__ W2,
                       u16* __restrict__ wb, int* __restrict__ deg8, int n) {
    int i = blockIdx.x * 256 + threadIdx.x;
    if (i < 32768) {
        int col = i >> 7, k = i & 127;
        float v = (col < 128) ? W1[k * 128 + col] : W2[k * 128 + (col - 128)];
        wb[i] = f2bf(v);
    }
    if (i < n) {
#pragma unroll
        for (int x = 0; x < SH; x++) deg8[x * n + i] = 0;
    }
}

// K2: blocks [0,Gg) = MFMA GEMM, blocks [Gg,Gg+Gc) = degree count + rank.
// rnk[i] = this edge's arrival index within its (shard,dst) slice.
// GEMM output packed: hbp[row][c] = (h2[c]<<16)|h1[c], c in [0,128)
__global__ __launch_bounds__(256) void k_cg(const float* __restrict__ x,
                                            const u16* __restrict__ wb,
                                            unsigned int* __restrict__ hbp, int n,
                                            const int* __restrict__ ei,
                                            int* __restrict__ deg8,
                                            int* __restrict__ rnk, int E, int Gg) {
    if ((int)blockIdx.x >= Gg) {
        int i = ((int)blockIdx.x - Gg) * 256 + threadIdx.x;
        if (i < E) {
            int sh = (i >> 8) & (SH - 1);
            int d = ei[E + i];
            rnk[i] = atomicAdd(&deg8[sh * n + d], 1);   // latency hidden by GEMM waves
        }
        return;
    }
    int wave = threadIdx.x >> 6, lane = threadIdx.x & 63;
    int quad = lane >> 4, r16 = lane & 15;
    int row = blockIdx.x * 64 + wave * 16 + r16;
    int arow = (row < n) ? row : n - 1;
    const float* xp = x + (size_t)arow * 128 + quad * 8;
    union { u16 u[8]; bf16x8 b; } ar;
    bf16x8 a[4];
#pragma unroll
    for (int ks = 0; ks < 4; ks++) {
        float4 lo = *(const float4*)(xp + ks * 32);
        float4 hi = *(const float4*)(xp + ks * 32 + 4);
        ar.u[0] = f2bf(lo.x); ar.u[1] = f2bf(lo.y); ar.u[2] = f2bf(lo.z); ar.u[3] = f2bf(lo.w);
        ar.u[4] = f2bf(hi.x); ar.u[5] = f2bf(hi.y); ar.u[6] = f2bf(hi.z); ar.u[7] = f2bf(hi.w);
        a[ks] = ar.b;
    }
    f32x4 acc[16];
#pragma unroll
    for (int t = 0; t < 16; t++) acc[t] = (f32x4){0.f, 0.f, 0.f, 0.f};
    const u16* bbase = wb + r16 * 128 + quad * 8;
#pragma unroll
    for (int t = 0; t < 16; t++) {
        const u16* bp = bbase + t * 2048;      // t*16 rows * 128
#pragma unroll
        for (int ks = 0; ks < 4; ks++) {
            bf16x8 b = *(const bf16x8*)(bp + ks * 32);
            acc[t] = __builtin_amdgcn_mfma_f32_16x16x32_bf16(a[ks], b, acc[t], 0, 0, 0);
        }
    }
    int row0 = blockIdx.x * 64 + wave * 16 + quad * 4;
#pragma unroll
    for (int t = 0; t < 8; t++) {
        int c = t * 16 + r16;                  // packed col 0..127
#pragma unroll
        for (int g = 0; g < 4; g++) {
            int gr = row0 + g;
            if (gr < n) {
                unsigned int pv = ((unsigned int)f2bf(acc[t + 8][g]) << 16) | f2bf(acc[t][g]);
                hbp[(size_t)gr * 128 + c] = pv;
            }
        }
    }
}

// bsum[b] = total degree of nodes in block b (input to k_scan phase 1)
__global__ void k_sb(const int* __restrict__ deg8, int* __restrict__ bsum, int n) {
    __shared__ int s[256];
    int i = blockIdx.x * 256 + threadIdx.x;
    int v = 0;
    if (i < n) {
#pragma unroll
        for (int x = 0; x < SH; x++) v += deg8[x * n + i];
    }
    s[threadIdx.x] = v;
    __syncthreads();
    for (int o = 128; o; o >>= 1) {
        if (threadIdx.x < o) s[threadIdx.x] += s[threadIdx.x + o];
        __syncthreads();
    }
    if (threadIdx.x == 0) bsum[blockIdx.x] = s[0];
}

// scan -> offs; deg8 converted IN-PLACE to per-shard slice starts:
// cursor[x][i] = offs[i] + sum_{y<x} deg[y][i]   (read-only afterwards)
__global__ void k_scan(int* __restrict__ deg8, const int* __restrict__ bsum,
                       int* __restrict__ offs, int nb, int n) {
    __shared__ int s[256];
    __shared__ int bp;
    int t = threadIdx.x;
    int bv = (t < nb) ? bsum[t] : 0;
    s[t] = bv;
    __syncthreads();
    for (int o = 1; o < 256; o <<= 1) {
        int u = (t >= o) ? s[t - o] : 0;
        __syncthreads();
        s[t] += u;
        __syncthreads();
    }
    if (t == (int)blockIdx.x) bp = s[t] - bv;   // exclusive prefix of this block
    __syncthreads();
    int i = blockIdx.x * 256 + t;
    int d[SH];
    int v = 0;
    if (i < n) {
#pragma unroll
        for (int x = 0; x < SH; x++) { d[x] = deg8[x * n + i]; v += d[x]; }
    }
    s[t] = v;
    __syncthreads();
    for (int o = 1; o < 256; o <<= 1) {
        int u = (t >= o) ? s[t - o] : 0;
        __syncthreads();
        s[t] += u;
        __syncthreads();
    }
    if (i < n) {
        int e = bp + s[t] - v;
        offs[i] = e;
        int run = e;
#pragma unroll
        for (int x = 0; x < SH; x++) { deg8[x * n + i] = run; run += d[x]; }
        if (i == n - 1) offs[n] = e + v;
    }
}

// K5: blocks [0,Gc) = atomic-free counting-sort placement (ssrc only),
// blocks [Gc,Gc+Gl) = per-(node,head) logits.
// es/ed rows: [node][head][layer] (slot = head*2+layer)
__global__ void k_fl(const int* __restrict__ ei, const int* __restrict__ cursor8,
                     const int* __restrict__ rnk,
                     int* __restrict__ ssrc, int E, int n,
                     const unsigned int* __restrict__ hbp,
                     const float* __restrict__ as1, const float* __restrict__ ad1,
                     const float* __restrict__ as2, const float* __restrict__ ad2,
                     float* __restrict__ es, float* __restrict__ ed, int Gc) {
    if ((int)blockIdx.x >= Gc) {
        int i = ((int)blockIdx.x - Gc) * 256 + threadIdx.x;
        if (i >= n * 4) return;
        int node = i >> 2, head = i & 3;
        const uint4* hv = (const uint4*)(hbp + (size_t)node * 128 + head * 32);
        const float* a1 = as1 + head * 32;
        const float* d1 = ad1 + head * 32;
        const float* a2 = as2 + head * 32;
        const float* d2 = ad2 + head * 32;
        float s1 = 0.f, t1 = 0.f, s2 = 0.f, t2 = 0.f;
#pragma unroll
        for (int q = 0; q < 8; q++) {
            uint4 w = hv[q];
            unsigned int ws[4] = {w.x, w.y, w.z, w.w};
#pragma unroll
            for (int h = 0; h < 4; h++) {
                int c = q * 4 + h;
                float v1 = bflo(ws[h]), v2 = bfhi(ws[h]);
                s1 += v1 * a1[c]; t1 += v1 * d1[c];
                s2 += v2 * a2[c]; t2 += v2 * d2[c];
            }
        }
        *(float2*)(es + node * 8 + head * 2) = make_float2(s1, s2);
        *(float2*)(ed + node * 8 + head * 2) = make_float2(t1, t2);
        return;
    }
    int i = blockIdx.x * 256 + threadIdx.x;
    if (i >= E) return;
    int s = ei[i], d = ei[E + i];
    int sh = (i >> 8) & (SH - 1);
    int pos = cursor8[sh * n + d] + rnk[i];
    ssrc[pos] = s;
}

__device__ __forceinline__ float wred(float v) {
#pragma unroll
    for (int off = 32; off; off >>= 1) v += __shfl_xor(v, off, 64);
    return v;
}

// one wave per node; lane owns packed cols ca=2*lane, cb=2*lane+1 (same head).
// Edge weights recomputed in-register: w = exp(lrelu(es[src]+ed[dst])).
__global__ __launch_bounds__(256) void k_agg(
    const int* __restrict__ offs, const int* __restrict__ ssrc,
    const unsigned int* __restrict__ hbp,
    const float* __restrict__ es, const float* __restrict__ ed,
    const float* __restrict__ b1, const float* __restrict__ b2,
    const float* __restrict__ gW, const float* __restrict__ gb,
    const float* __restrict__ x, const float* __restrict__ gamma,
    const float* __restrict__ beta, float* __restrict__ out, int n) {
    int wave = threadIdx.x >> 6, lane = threadIdx.x & 63;
    int node = blockIdx.x * 4 + wave;
    if (node >= n) return;
    node = __builtin_amdgcn_readfirstlane(node);   // wave-uniform -> s_loads

    int ca = lane * 2;
    int head = lane >> 4;                  // = ca>>5
    int hh = head * 2;                     // slot base in es/ed rows

    float2 edv = *(const float2*)(ed + node * 8 + hh);
    float ed1 = edv.x, ed2 = edv.y;        // dst logit terms, loop-invariant

    float l1 = 0.f, l2 = 0.f;
    float a1a = 0.f, a1b = 0.f, a2a = 0.f, a2b = 0.f;

#define EDGE(sv, q) { \
        float e1 = sv.x + ed1; e1 = fmaxf(e1, LRELU_SLOPE * e1); \
        float e2 = sv.y + ed2; e2 = fmaxf(e2, LRELU_SLOPE * e2); \
        float ww1 = __expf(e1), ww2 = __expf(e2); \
        l1 += ww1; l2 += ww2; \
        a1a += ww1 * bflo(q.x); a1b += ww1 * bflo(q.y); \
        a2a += ww2 * bfhi(q.x); a2b += ww2 * bfhi(q.y); }

    // self-loop (es/ed rows of this node, coalesced hbp row read)
    {
        float2 svs = *(const float2*)(es + node * 8 + hh);
        uint2 qs = *(const uint2*)(hbp + (size_t)node * 128 + ca);
        EDGE(svs, qs)
    }

    int beg = offs[node], end = offs[node + 1];
    int k = beg;
    for (; k + 3 < end; k += 4) {
        int j0 = ssrc[k], j1 = ssrc[k + 1], j2 = ssrc[k + 2], j3 = ssrc[k + 3];
        float2 s0 = *(const float2*)(es + j0 * 8 + hh);
        float2 s1 = *(const float2*)(es + j1 * 8 + hh);
        float2 s2 = *(const float2*)(es + j2 * 8 + hh);
        float2 s3 = *(const float2*)(es + j3 * 8 + hh);
        uint2 q0 = *(const uint2*)(hbp + (size_t)j0 * 128 + ca);
        uint2 q1 = *(const uint2*)(hbp + (size_t)j1 * 128 + ca);
        uint2 q2 = *(const uint2*)(hbp + (size_t)j2 * 128 + ca);
        uint2 q3 = *(const uint2*)(hbp + (size_t)j3 * 128 + ca);
        EDGE(s0, q0) EDGE(s1, q1) EDGE(s2, q2) EDGE(s3, q3)
    }
    for (; k < end; k++) {
        int j = ssrc[k];
        float2 sv = *(const float2*)(es + j * 8 + hh);
        uint2 q = *(const uint2*)(hbp + (size_t)j * 128 + ca);
        EDGE(sv, q)
    }
#undef EDGE

    float2 b1v = *(const float2*)(b1 + ca);
    float2 b2v = *(const float2*)(b2 + ca);
    float r1 = 1.f / l1, r2 = 1.f / l2;
    float o1a = a1a * r1 + b1v.x;
    float o1b = a1b * r1 + b1v.y;
    float o2a = a2a * r2 + b2v.x;
    float o2b = a2b * r2 + b2v.y;

    // gate logits: concat(out1,out2) @ gate_W(256x2) + gate_b
    int cb = ca + 1;
    float2 g1a = *(const float2*)(gW + 2 * ca);          // rows ca,cb
    float2 g1b = *(const float2*)(gW + 2 * cb);
    float2 g2a = *(const float2*)(gW + 2 * (128 + ca));
    float2 g2b = *(const float2*)(gW + 2 * (128 + cb));
    float p0 = o1a * g1a.x + o1b * g1b.x + o2a * g2a.x + o2b * g2b.x;
    float p1 = o1a * g1a.y + o1b * g1b.y + o2a * g2a.y + o2b * g2b.y;
    p0 = wred(p0) + gb[0];
    p1 = wred(p1) + gb[1];
    float mg = fmaxf(p0, p1);
    float eg0 = __expf(p0 - mg), eg1 = __expf(p1 - mg);
    float g0 = eg0 / (eg0 + eg1), g1 = 1.f - g0;

    float2 xv = *(const float2*)(x + (size_t)node * 128 + ca);
    float ya = xv.x + g0 * o1a + g1 * o2a;
    float yb = xv.y + g0 * o1b + g1 * o2b;

    float s  = wred(ya + yb);
    float ss = wred(ya * ya + yb * yb);
    float mean = s * (1.f / 128.f);
    float var  = ss * (1.f / 128.f) - mean * mean;
    float rstd = rsqrtf(var + LN_EPS);
    float2 gv = *(const float2*)(gamma + ca);
    float2 bv = *(const float2*)(beta + ca);
    float2 ov;
    ov.x = (ya - mean) * rstd * gv.x + bv.x;
    ov.y = (yb - mean) * rstd * gv.y + bv.y;
    *(float2*)(out + (size_t)node * 128 + ca) = ov;
}

extern "C" void kernel_launch(void* const* d_in, const int* in_sizes, int n_in,
                              void* d_out, int out_size, void* d_ws, size_t ws_size,
                              hipStream_t stream) {
    const float* x   = (const float*)d_in[0];
    const int*   ei  = (const int*)d_in[1];
    const float* W1  = (const float*)d_in[2];
    const float* b1  = (const float*)d_in[3];
    const float* as1 = (const float*)d_in[4];
    const float* ad1 = (const float*)d_in[5];
    const float* W2  = (const float*)d_in[6];
    const float* b2  = (const float*)d_in[7];
    const float* as2 = (const float*)d_in[8];
    const float* ad2 = (const float*)d_in[9];
    const float* gW  = (const float*)d_in[10];
    const float* gb  = (const float*)d_in[11];
    const float* gamma = (const float*)d_in[12];
    const float* beta  = (const float*)d_in[13];
    float* out = (float*)d_out;

    int n = in_sizes[0] / 128;
    int E = in_sizes[1] / 2;

    char* p = (char*)d_ws;
    auto take = [&](size_t bytes) {
        char* q = p;
        p += (bytes + 255) & ~(size_t)255;
        return (void*)q;
    };
    u16* wb    = (u16*)take((size_t)256 * 128 * 2);
    unsigned int* hbp = (unsigned int*)take((size_t)n * 128 * 4);
    float* es  = (float*)take((size_t)n * 8 * 4);
    float* ed  = (float*)take((size_t)n * 8 * 4);
    int* deg8  = (int*)take((size_t)SH * n * 4);   // becomes slice-start cursors after k_scan
    int* offs  = (int*)take((size_t)(n + 1) * 4);
    int* bsum  = (int*)take((size_t)256 * 4);
    int* ssrc  = (int*)take((size_t)E * 4);
    int* rnk   = (int*)take((size_t)E * 4);

    int nb = (n + 255) / 256;       // 196 (<= 256 required by k_scan)
    int Gg = (n + 63) / 64;         // gemm blocks
    int Gc = (E + 255) / 256;       // count/sort blocks
    int Gl = (n * 4 + 255) / 256;   // logits blocks

    k_prep<<<nb, 256, 0, stream>>>(W1, W2, wb, deg8, n);
    k_cg<<<Gg + Gc, 256, 0, stream>>>(x, wb, hbp, n, ei, deg8, rnk, E, Gg);
    k_sb<<<nb, 256, 0, stream>>>(deg8, bsum, n);
    k_scan<<<nb, 256, 0, stream>>>(deg8, bsum, offs, nb, n);
    k_fl<<<Gc + Gl, 256, 0, stream>>>(ei, deg8, rnk, ssrc, E, n, hbp,
                                      as1, ad1, as2, ad2, es, ed, Gc);
    k_agg<<<(n + 3) / 4, 256, 0, stream>>>(offs, ssrc, hbp, es, ed,
                                           b1, b2, gW, gb, x, gamma, beta, out, n);
}

// Round 3
// 258.312 us; speedup vs baseline: 1.1456x; 1.0086x over previous
//
#include <hip/hip_runtime.h>
#include <hip/hip_bf16.h>

// GraphAttentionEncoder: 2x GATConv (shared edges) + gated mix + residual + LN
// N=50000, DIM=128, H=4, C=32, E=800000 (+N self loops)
//
// R9 changes vs R8:
//  - k_cg GEMM: wb (64KB B-operand) staged in LDS once per block instead of
//    re-read from L2 per wave (was ~800MB L2 traffic). wb is PRE-PERMUTED by
//    k_prep so each (t,ks) fragment is a contiguous conflict-free 1KB chunk.
//    Blocks now process 128 rows (2 strips) to amortize staging.
//  - count phase: 4 edges/thread (MLP compensates 64KB-LDS occupancy cap);
//    rank packed as (rnk<<17)|dst -> k_fl sort reads 2 streams not 3.
//  - k_sb+k_scan fused into k_ss (device-scope flag + spin; 196 blocks all
//    co-resident). bsum re-read via atomics (cross-XCD/replay staleness).
//  - k_agg: x8 unroll (16 loads in flight) + nontemporal out store (keep L2
//    for hbp/es gathers).

typedef unsigned short u16;
typedef __bf16 bf16x8 __attribute__((ext_vector_type(8)));
typedef float f32x4 __attribute__((ext_vector_type(4)));

#define LRELU_SLOPE 0.2f
#define LN_EPS 1e-5f
#define SH 8                 // atomic shards

__device__ __forceinline__ float bfbits(unsigned int hi_bits) {
    union { unsigned int i; float f; } v; v.i = hi_bits; return v.f;
}
__device__ __forceinline__ float bflo(unsigned int u) { return bfbits(u << 16); }
__device__ __forceinline__ float bfhi(unsigned int u) { return bfbits(u & 0xFFFF0000u); }
__device__ __forceinline__ u16 f2bf(float f) {
    union { float f; unsigned int i; } v; v.f = f;
    unsigned int lsb = (v.i >> 16) & 1u;
    v.i += 0x7FFFu + lsb;                 // round-to-nearest-even
    return (u16)(v.i >> 16);
}

// wb permuted for LDS: u16 index i -> chunk=i>>3 (16B), e=i&7.
// chunk = (t*4+ks)*64 + lane, lane=quad*16+r16. Element = W[k][col'] with
// col' = t*16+r16 (0-127 -> W1, 128-255 -> W2), k = quad*8+ks*32+e.
// Matches k_cg's b-fragment (lane holds wb_orig[col'*128 + quad*8+ks*32+e]).
__global__ void k_prep(const float* __restrict__ W1, const float* __restrict__ W2,
                       u16* __restrict__ wb, int* __restrict__ deg8,
                       int* __restrict__ gflag, int n) {
    int i = blockIdx.x * 256 + threadIdx.x;
    if (i < 32768) {
        int e = i & 7, chunk = i >> 3;
        int lane = chunk & 63, ks = (chunk >> 6) & 3, t = chunk >> 8;
        int r16 = lane & 15, quad = lane >> 4;
        int colp = t * 16 + r16;
        int k = quad * 8 + ks * 32 + e;
        float v = (colp < 128) ? W1[k * 128 + colp] : W2[k * 128 + (colp - 128)];
        wb[i] = f2bf(v);
    }
    if (i < n) {
#pragma unroll
        for (int x = 0; x < SH; x++) deg8[x * n + i] = 0;
    }
    if (i == 0) *gflag = 0;
}

// K2: blocks [0,Gg) = MFMA GEMM (128 rows/block, LDS-staged B),
// blocks [Gg,..) = degree count + packed rank (1024 edges/block).
// GEMM output packed: hbp[row][c] = (h2[c]<<16)|h1[c], c in [0,128)
__global__ __launch_bounds__(256) void k_cg(const float* __restrict__ x,
                                            const u16* __restrict__ wb,
                                            unsigned int* __restrict__ hbp, int n,
                                            const int* __restrict__ ei,
                                            int* __restrict__ deg8,
                                            unsigned int* __restrict__ pk,
                                            int E, int Gg) {
    __shared__ u16 lwb[32768];
    if ((int)blockIdx.x >= Gg) {
        int bid = (int)blockIdx.x - Gg;
#pragma unroll
        for (int it = 0; it < 4; it++) {
            int i = bid * 1024 + it * 256 + threadIdx.x;
            if (i < E) {
                int d = ei[E + i];
                int sh = (i >> 8) & (SH - 1);
                unsigned int r = (unsigned int)atomicAdd(&deg8[sh * n + d], 1);
                pk[i] = (r << 17) | (unsigned int)d;
            }
        }
        return;
    }
    {   // stage B: 64KB, linear copy (permutation already applied by k_prep)
        const uint4* g = (const uint4*)wb;
        uint4* l = (uint4*)lwb;
#pragma unroll
        for (int r = 0; r < 16; r++) l[r * 256 + threadIdx.x] = g[r * 256 + threadIdx.x];
    }
    __syncthreads();
    int wave = threadIdx.x >> 6, lane = threadIdx.x & 63;
    int quad = lane >> 4, r16 = lane & 15;
    const u16* bb = lwb + lane * 8;        // + (t*4+ks)*512
    for (int strip = 0; strip < 2; strip++) {
        int row = blockIdx.x * 128 + strip * 64 + wave * 16 + r16;
        int arow = (row < n) ? row : n - 1;
        const float* xp = x + (size_t)arow * 128 + quad * 8;
        union { u16 u[8]; bf16x8 b; } ar;
        bf16x8 a[4];
#pragma unroll
        for (int ks = 0; ks < 4; ks++) {
            float4 lo = *(const float4*)(xp + ks * 32);
            float4 hi = *(const float4*)(xp + ks * 32 + 4);
            ar.u[0] = f2bf(lo.x); ar.u[1] = f2bf(lo.y); ar.u[2] = f2bf(lo.z); ar.u[3] = f2bf(lo.w);
            ar.u[4] = f2bf(hi.x); ar.u[5] = f2bf(hi.y); ar.u[6] = f2bf(hi.z); ar.u[7] = f2bf(hi.w);
            a[ks] = ar.b;
        }
        f32x4 acc[16];
#pragma unroll
        for (int t = 0; t < 16; t++) acc[t] = (f32x4){0.f, 0.f, 0.f, 0.f};
#pragma unroll
        for (int t = 0; t < 16; t++) {
#pragma unroll
            for (int ks = 0; ks < 4; ks++) {
                bf16x8 b = *(const bf16x8*)(bb + (t * 4 + ks) * 512);
                acc[t] = __builtin_amdgcn_mfma_f32_16x16x32_bf16(a[ks], b, acc[t], 0, 0, 0);
            }
        }
        int row0 = blockIdx.x * 128 + strip * 64 + wave * 16 + quad * 4;
#pragma unroll
        for (int t = 0; t < 8; t++) {
            int c = t * 16 + r16;              // packed col 0..127
#pragma unroll
            for (int g = 0; g < 4; g++) {
                int gr = row0 + g;
                if (gr < n) {
                    unsigned int pv = ((unsigned int)f2bf(acc[t + 8][g]) << 16) | f2bf(acc[t][g]);
                    hbp[(size_t)gr * 128 + c] = pv;
                }
            }
        }
    }
}

// Fused bsum + scan: phase A each block computes its total and publishes;
// all blocks spin on device-scope flag (196 blocks, all co-resident);
// phase B computes block prefix from bsum and finishes per-node scan.
// deg8 converted IN-PLACE to per-shard slice starts.
__global__ void k_ss(int* __restrict__ deg8, int* __restrict__ offs,
                     int* __restrict__ bsum, int* __restrict__ gflag,
                     int nb, int n) {
    __shared__ int s[256];
    int t = threadIdx.x;
    int i = blockIdx.x * 256 + t;
    int d[SH];
    int v = 0;
    if (i < n) {
#pragma unroll
        for (int x = 0; x < SH; x++) { d[x] = deg8[x * n + i]; v += d[x]; }
    }
    s[t] = v;
    __syncthreads();
    for (int o = 1; o < 256; o <<= 1) {
        int u = (t >= o) ? s[t - o] : 0;
        __syncthreads();
        s[t] += u;
        __syncthreads();
    }
    int myinc = s[t];
    int total = s[255];
    if (t == 0) {
        bsum[blockIdx.x] = total;
        __threadfence();
        atomicAdd(gflag, 1);
        while (atomicAdd(gflag, 0) < nb) { }
    }
    __syncthreads();
    // block prefix = sum of bsum[0..blockIdx) (device-scope reads: fresh)
    int bv = (t < (int)blockIdx.x) ? atomicAdd(&bsum[t], 0) : 0;
    s[t] = bv;
    __syncthreads();
    for (int o = 128; o; o >>= 1) {
        if (t < o) s[t] += s[t + o];
        __syncthreads();
    }
    int bp = s[0];
    if (i < n) {
        int e = bp + myinc - v;
        offs[i] = e;
        int run = e;
#pragma unroll
        for (int x = 0; x < SH; x++) { deg8[x * n + i] = run; run += d[x]; }
        if (i == n - 1) offs[n] = e + v;
    }
}

// K4: blocks [0,Gc) = atomic-free counting-sort placement (1024 edges/block),
// blocks [Gc,..) = per-(node,head) logits.
// es/ed rows: [node][head][layer] (slot = head*2+layer)
__global__ void k_fl(const int* __restrict__ ei, const int* __restrict__ cursor8,
                     const unsigned int* __restrict__ pk,
                     int* __restrict__ ssrc, int E, int n,
                     const unsigned int* __restrict__ hbp,
                     const float* __restrict__ as1, const float* __restrict__ ad1,
                     const float* __restrict__ as2, const float* __restrict__ ad2,
                     float* __restrict__ es, float* __restrict__ ed, int Gc) {
    if ((int)blockIdx.x >= Gc) {
        int i = ((int)blockIdx.x - Gc) * 256 + threadIdx.x;
        if (i >= n * 4) return;
        int node = i >> 2, head = i & 3;
        const uint4* hv = (const uint4*)(hbp + (size_t)node * 128 + head * 32);
        const float* a1 = as1 + head * 32;
        const float* d1 = ad1 + head * 32;
        const float* a2 = as2 + head * 32;
        const float* d2 = ad2 + head * 32;
        float s1 = 0.f, t1 = 0.f, s2 = 0.f, t2 = 0.f;
#pragma unroll
        for (int q = 0; q < 8; q++) {
            uint4 w = hv[q];
            unsigned int ws[4] = {w.x, w.y, w.z, w.w};
#pragma unroll
            for (int h = 0; h < 4; h++) {
                int c = q * 4 + h;
                float v1 = bflo(ws[h]), v2 = bfhi(ws[h]);
                s1 += v1 * a1[c]; t1 += v1 * d1[c];
                s2 += v2 * a2[c]; t2 += v2 * d2[c];
            }
        }
        *(float2*)(es + node * 8 + head * 2) = make_float2(s1, s2);
        *(float2*)(ed + node * 8 + head * 2) = make_float2(t1, t2);
        return;
    }
#pragma unroll
    for (int it = 0; it < 4; it++) {
        int i = blockIdx.x * 1024 + it * 256 + threadIdx.x;
        if (i < E) {
            int s = ei[i];
            unsigned int v = pk[i];
            int d = (int)(v & 0x1FFFFu);
            int r = (int)(v >> 17);
            int sh = (i >> 8) & (SH - 1);
            ssrc[cursor8[sh * n + d] + r] = s;
        }
    }
}

__device__ __forceinline__ float wred(float v) {
#pragma unroll
    for (int off = 32; off; off >>= 1) v += __shfl_xor(v, off, 64);
    return v;
}

// one wave per node; lane owns packed cols ca=2*lane, cb=2*lane+1 (same head).
// Edge weights recomputed in-register: w = exp(lrelu(es[src]+ed[dst])).
__global__ __launch_bounds__(256) void k_agg(
    const int* __restrict__ offs, const int* __restrict__ ssrc,
    const unsigned int* __restrict__ hbp,
    const float* __restrict__ es, const float* __restrict__ ed,
    const float* __restrict__ b1, const float* __restrict__ b2,
    const float* __restrict__ gW, const float* __restrict__ gb,
    const float* __restrict__ x, const float* __restrict__ gamma,
    const float* __restrict__ beta, float* __restrict__ out, int n) {
    int wave = threadIdx.x >> 6, lane = threadIdx.x & 63;
    int node = blockIdx.x * 4 + wave;
    if (node >= n) return;
    node = __builtin_amdgcn_readfirstlane(node);   // wave-uniform -> s_loads

    int ca = lane * 2;
    int head = lane >> 4;                  // = ca>>5
    int hh = head * 2;                     // slot base in es/ed rows

    float2 edv = *(const float2*)(ed + node * 8 + hh);
    float ed1 = edv.x, ed2 = edv.y;        // dst logit terms, loop-invariant

    float l1 = 0.f, l2 = 0.f;
    float a1a = 0.f, a1b = 0.f, a2a = 0.f, a2b = 0.f;

#define EDGE(sv, q) { \
        float e1 = sv.x + ed1; e1 = fmaxf(e1, LRELU_SLOPE * e1); \
        float e2 = sv.y + ed2; e2 = fmaxf(e2, LRELU_SLOPE * e2); \
        float ww1 = __expf(e1), ww2 = __expf(e2); \
        l1 += ww1; l2 += ww2; \
        a1a += ww1 * bflo(q.x); a1b += ww1 * bflo(q.y); \
        a2a += ww2 * bfhi(q.x); a2b += ww2 * bfhi(q.y); }

    // self-loop (es/ed rows of this node, coalesced hbp row read)
    {
        float2 svs = *(const float2*)(es + node * 8 + hh);
        uint2 qs = *(const uint2*)(hbp + (size_t)node * 128 + ca);
        EDGE(svs, qs)
    }

    int beg = offs[node], end = offs[node + 1];
    int k = beg;
    for (; k + 7 < end; k += 8) {
        int jj[8];
#pragma unroll
        for (int u = 0; u < 8; u++) jj[u] = ssrc[k + u];
        float2 sv[8];
#pragma unroll
        for (int u = 0; u < 8; u++) sv[u] = *(const float2*)(es + jj[u] * 8 + hh);
        uint2 qq[8];
#pragma unroll
        for (int u = 0; u < 8; u++) qq[u] = *(const uint2*)(hbp + (size_t)jj[u] * 128 + ca);
#pragma unroll
        for (int u = 0; u < 8; u++) EDGE(sv[u], qq[u])
    }
    if (k + 3 < end) {
        int jj[4];
#pragma unroll
        for (int u = 0; u < 4; u++) jj[u] = ssrc[k + u];
        float2 sv[4];
#pragma unroll
        for (int u = 0; u < 4; u++) sv[u] = *(const float2*)(es + jj[u] * 8 + hh);
        uint2 qq[4];
#pragma unroll
        for (int u = 0; u < 4; u++) qq[u] = *(const uint2*)(hbp + (size_t)jj[u] * 128 + ca);
#pragma unroll
        for (int u = 0; u < 4; u++) EDGE(sv[u], qq[u])
        k += 4;
    }
    for (; k < end; k++) {
        int j = ssrc[k];
        float2 sv = *(const float2*)(es + j * 8 + hh);
        uint2 q = *(const uint2*)(hbp + (size_t)j * 128 + ca);
        EDGE(sv, q)
    }
#undef EDGE

    float2 b1v = *(const float2*)(b1 + ca);
    float2 b2v = *(const float2*)(b2 + ca);
    float r1 = 1.f / l1, r2 = 1.f / l2;
    float o1a = a1a * r1 + b1v.x;
    float o1b = a1b * r1 + b1v.y;
    float o2a = a2a * r2 + b2v.x;
    float o2b = a2b * r2 + b2v.y;

    // gate logits: concat(out1,out2) @ gate_W(256x2) + gate_b
    int cb = ca + 1;
    float2 g1a = *(const float2*)(gW + 2 * ca);          // rows ca,cb
    float2 g1b = *(const float2*)(gW + 2 * cb);
    float2 g2a = *(const float2*)(gW + 2 * (128 + ca));
    float2 g2b = *(const float2*)(gW + 2 * (128 + cb));
    float p0 = o1a * g1a.x + o1b * g1b.x + o2a * g2a.x + o2b * g2b.x;
    float p1 = o1a * g1a.y + o1b * g1b.y + o2a * g2a.y + o2b * g2b.y;
    p0 = wred(p0) + gb[0];
    p1 = wred(p1) + gb[1];
    float mg = fmaxf(p0, p1);
    float eg0 = __expf(p0 - mg), eg1 = __expf(p1 - mg);
    float g0 = eg0 / (eg0 + eg1), g1 = 1.f - g0;

    float2 xv = *(const float2*)(x + (size_t)node * 128 + ca);
    float ya = xv.x + g0 * o1a + g1 * o2a;
    float yb = xv.y + g0 * o1b + g1 * o2b;

    float s  = wred(ya + yb);
    float ss = wred(ya * ya + yb * yb);
    float mean = s * (1.f / 128.f);
    float var  = ss * (1.f / 128.f) - mean * mean;
    float rstd = rsqrtf(var + LN_EPS);
    float2 gv = *(const float2*)(gamma + ca);
    float2 bv = *(const float2*)(beta + ca);
    union { float2 f2; double d; } ov;
    ov.f2.x = (ya - mean) * rstd * gv.x + bv.x;
    ov.f2.y = (yb - mean) * rstd * gv.y + bv.y;
    // nontemporal: out is never re-read; keep L2 for hbp/es gathers
    __builtin_nontemporal_store(ov.d, (double*)(out + (size_t)node * 128 + ca));
}

extern "C" void kernel_launch(void* const* d_in, const int* in_sizes, int n_in,
                              void* d_out, int out_size, void* d_ws, size_t ws_size,
                              hipStream_t stream) {
    const float* x   = (const float*)d_in[0];
    const int*   ei  = (const int*)d_in[1];
    const float* W1  = (const float*)d_in[2];
    const float* b1  = (const float*)d_in[3];
    const float* as1 = (const float*)d_in[4];
    const float* ad1 = (const float*)d_in[5];
    const float* W2  = (const float*)d_in[6];
    const float* b2  = (const float*)d_in[7];
    const float* as2 = (const float*)d_in[8];
    const float* ad2 = (const float*)d_in[9];
    const float* gW  = (const float*)d_in[10];
    const float* gb  = (const float*)d_in[11];
    const float* gamma = (const float*)d_in[12];
    const float* beta  = (const float*)d_in[13];
    float* out = (float*)d_out;

    int n = in_sizes[0] / 128;
    int E = in_sizes[1] / 2;

    char* p = (char*)d_ws;
    auto take = [&](size_t bytes) {
        char* q = p;
        p += (bytes + 255) & ~(size_t)255;
        return (void*)q;
    };
    u16* wb    = (u16*)take((size_t)256 * 128 * 2);
    unsigned int* hbp = (unsigned int*)take((size_t)n * 128 * 4);
    float* es  = (float*)take((size_t)n * 8 * 4);
    float* ed  = (float*)take((size_t)n * 8 * 4);
    int* deg8  = (int*)take((size_t)SH * n * 4);   // becomes slice-start cursors after k_ss
    int* offs  = (int*)take((size_t)(n + 1) * 4);
    int* bsum  = (int*)take((size_t)256 * 4);
    int* gflag = (int*)take((size_t)256 * 4);
    int* ssrc  = (int*)take((size_t)E * 4);
    unsigned int* pk = (unsigned int*)take((size_t)E * 4);

    int nb  = (n + 255) / 256;      // 196 (<= 256 required by k_ss)
    int Gg  = (n + 127) / 128;      // gemm blocks (128 rows each)
    int Gcc = (E + 1023) / 1024;    // count/sort blocks (1024 edges each)
    int Gl  = (n * 4 + 255) / 256;  // logits blocks

    k_prep<<<nb, 256, 0, stream>>>(W1, W2, wb, deg8, gflag, n);
    k_cg<<<Gg + Gcc, 256, 0, stream>>>(x, wb, hbp, n, ei, deg8, pk, E, Gg);
    k_ss<<<nb, 256, 0, stream>>>(deg8, offs, bsum, gflag, nb, n);
    k_fl<<<Gcc + Gl, 256, 0, stream>>>(ei, deg8, pk, ssrc, E, n, hbp,
                                       as1, ad1, as2, ad2, es, ed, Gcc);
    k_agg<<<(n + 3) / 4, 256, 0, stream>>>(offs, ssrc, hbp, es, ed,
                                           b1, b2, gW, gb, x, gamma, beta, out, n);
}

// Round 4
// 255.995 us; speedup vs baseline: 1.1560x; 1.0091x over previous
//
#include <hip/hip_runtime.h>
#include <hip/hip_bf16.h>

// GraphAttentionEncoder: 2x GATConv (shared edges) + gated mix + residual + LN
// N=50000, DIM=128, H=4, C=32, E=800000 (+N self loops)
//
// R10 changes vs R9:
//  - es/ed (attention logits) computed in k_cg's GEMM epilogue from the f32
//    accumulators (4-step shfl_xor reduce-scatter over the 16 r16-lanes;
//    lane r16 ends with slot r16 and stores directly). Kills k_fl's 25.6MB
//    hbp re-read; es/ed now f32-exact.
//  - count+rank moved to k_pc (NO LDS -> full occupancy for the atomic
//    phase; R9 accidentally capped it at 2 blocks/CU via the 64KB lwb).
//    8 edges/thread for atomic MLP. deg8 zeroed via hipMemsetAsync.
//  - scan runs as 196 trailing blocks of k_cg's grid (spin protocol
//    unchanged; GEMM blocks never wait -> slots drain -> no deadlock).
//  - k_fl = counting-sort placement only.
//  - k_agg: revert to R8 x4 unroll (24 VGPR / 70% occ; R9's x8 cost 17%
//    occupancy for nothing), keep nontemporal out store.

typedef unsigned short u16;
typedef __bf16 bf16x8 __attribute__((ext_vector_type(8)));
typedef float f32x4 __attribute__((ext_vector_type(4)));

#define LRELU_SLOPE 0.2f
#define LN_EPS 1e-5f
#define SH 8                 // atomic shards

__device__ __forceinline__ float bfbits(unsigned int hi_bits) {
    union { unsigned int i; float f; } v; v.i = hi_bits; return v.f;
}
__device__ __forceinline__ float bflo(unsigned int u) { return bfbits(u << 16); }
__device__ __forceinline__ float bfhi(unsigned int u) { return bfbits(u & 0xFFFF0000u); }
__device__ __forceinline__ u16 f2bf(float f) {
    union { float f; unsigned int i; } v; v.f = f;
    unsigned int lsb = (v.i >> 16) & 1u;
    v.i += 0x7FFFu + lsb;                 // round-to-nearest-even
    return (u16)(v.i >> 16);
}

// K1: blocks [0,128) = wb permute (see R9 comment: chunk=(t*4+ks)*64+lane,
// lane=quad*16+r16, elem k=quad*8+ks*32+e, col'=t*16+r16) + gflag zero.
// blocks [128,..) = degree count + packed rank pk=(rnk<<17)|dst,
// 2048 edges/block (8/thread, deep atomic MLP, no LDS).
__global__ void k_pc(const float* __restrict__ W1, const float* __restrict__ W2,
                     u16* __restrict__ wb, int* __restrict__ deg8,
                     int* __restrict__ gflag,
                     const int* __restrict__ ei, unsigned int* __restrict__ pk,
                     int E, int n) {
    if (blockIdx.x < 128) {
        int i = blockIdx.x * 256 + threadIdx.x;
        int e = i & 7, chunk = i >> 3;
        int lane = chunk & 63, ks = (chunk >> 6) & 3, t = chunk >> 8;
        int r16 = lane & 15, quad = lane >> 4;
        int colp = t * 16 + r16;
        int k = quad * 8 + ks * 32 + e;
        float v = (colp < 128) ? W1[k * 128 + colp] : W2[k * 128 + (colp - 128)];
        wb[i] = f2bf(v);
        if (i == 0) *gflag = 0;
        return;
    }
    int bid = (int)blockIdx.x - 128;
#pragma unroll
    for (int it = 0; it < 8; it++) {
        int i = bid * 2048 + it * 256 + threadIdx.x;
        if (i < E) {
            int d = ei[E + i];
            int sh = (i >> 8) & (SH - 1);
            unsigned int r = (unsigned int)atomicAdd(&deg8[sh * n + d], 1);
            pk[i] = (r << 17) | (unsigned int)d;
        }
    }
}

// K2: blocks [0,Gg) = MFMA GEMM (128 rows/block, LDS-staged B) with fused
// es/ed epilogue; blocks [Gg,Gg+nb) = fused bsum+scan (spin on gflag).
// GEMM output packed: hbp[row][c] = (h2[c]<<16)|h1[c], c in [0,128)
// es/ed rows: [node][head*2+layer], computed from f32 acc.
__global__ __launch_bounds__(256) void k_cg(const float* __restrict__ x,
                                            const u16* __restrict__ wb,
                                            unsigned int* __restrict__ hbp, int n,
                                            const float* __restrict__ as1,
                                            const float* __restrict__ ad1,
                                            const float* __restrict__ as2,
                                            const float* __restrict__ ad2,
                                            float* __restrict__ es,
                                            float* __restrict__ ed,
                                            int* __restrict__ deg8,
                                            int* __restrict__ offs,
                                            int* __restrict__ bsum,
                                            int* __restrict__ gflag,
                                            int nb, int Gg) {
    __shared__ u16 lwb[32768];
    if ((int)blockIdx.x >= Gg) {
        // ---- scan blocks (alias lwb as int scratch) ----
        int* si = (int*)lwb;
        int bblk = (int)blockIdx.x - Gg;
        int t = threadIdx.x;
        int i = bblk * 256 + t;
        int d[SH];
        int v = 0;
        if (i < n) {
#pragma unroll
            for (int xx = 0; xx < SH; xx++) { d[xx] = deg8[xx * n + i]; v += d[xx]; }
        }
        si[t] = v;
        __syncthreads();
        for (int o = 1; o < 256; o <<= 1) {
            int u = (t >= o) ? si[t - o] : 0;
            __syncthreads();
            si[t] += u;
            __syncthreads();
        }
        int myinc = si[t];
        int total = si[255];
        if (t == 0) {
            bsum[bblk] = total;
            __threadfence();
            atomicAdd(gflag, 1);
            while (atomicAdd(gflag, 0) < nb) __builtin_amdgcn_s_sleep(8);
        }
        __syncthreads();
        int bv = (t < bblk) ? atomicAdd(&bsum[t], 0) : 0;
        si[t] = bv;
        __syncthreads();
        for (int o = 128; o; o >>= 1) {
            if (t < o) si[t] += si[t + o];
            __syncthreads();
        }
        int bp = si[0];
        if (i < n) {
            int e = bp + myinc - v;
            offs[i] = e;
            int run = e;
#pragma unroll
            for (int xx = 0; xx < SH; xx++) { deg8[xx * n + i] = run; run += d[xx]; }
            if (i == n - 1) offs[n] = e + v;
        }
        return;
    }
    {   // stage B: 64KB, linear copy (permutation already applied by k_pc)
        const uint4* g = (const uint4*)wb;
        uint4* l = (uint4*)lwb;
#pragma unroll
        for (int r = 0; r < 16; r++) l[r * 256 + threadIdx.x] = g[r * 256 + threadIdx.x];
    }
    __syncthreads();
    int wave = threadIdx.x >> 6, lane = threadIdx.x & 63;
    int quad = lane >> 4, r16 = lane & 15;
    const u16* bb = lwb + lane * 8;        // + (t*4+ks)*512
    // att vectors for this lane's two cols per head (c=r16 and c=16+r16)
    float2 aS1[4], aD1[4], aS2[4], aD2[4];
#pragma unroll
    for (int h = 0; h < 4; h++) {
        aS1[h] = make_float2(as1[h * 32 + r16], as1[h * 32 + 16 + r16]);
        aD1[h] = make_float2(ad1[h * 32 + r16], ad1[h * 32 + 16 + r16]);
        aS2[h] = make_float2(as2[h * 32 + r16], as2[h * 32 + 16 + r16]);
        aD2[h] = make_float2(ad2[h * 32 + r16], ad2[h * 32 + 16 + r16]);
    }
    for (int strip = 0; strip < 2; strip++) {
        int row = blockIdx.x * 128 + strip * 64 + wave * 16 + r16;
        int arow = (row < n) ? row : n - 1;
        const float* xp = x + (size_t)arow * 128 + quad * 8;
        union { u16 u[8]; bf16x8 b; } ar;
        bf16x8 a[4];
#pragma unroll
        for (int ks = 0; ks < 4; ks++) {
            float4 lo = *(const float4*)(xp + ks * 32);
            float4 hi = *(const float4*)(xp + ks * 32 + 4);
            ar.u[0] = f2bf(lo.x); ar.u[1] = f2bf(lo.y); ar.u[2] = f2bf(lo.z); ar.u[3] = f2bf(lo.w);
            ar.u[4] = f2bf(hi.x); ar.u[5] = f2bf(hi.y); ar.u[6] = f2bf(hi.z); ar.u[7] = f2bf(hi.w);
            a[ks] = ar.b;
        }
        f32x4 acc[16];
#pragma unroll
        for (int t = 0; t < 16; t++) acc[t] = (f32x4){0.f, 0.f, 0.f, 0.f};
#pragma unroll
        for (int t = 0; t < 16; t++) {
#pragma unroll
            for (int ks = 0; ks < 4; ks++) {
                bf16x8 b = *(const bf16x8*)(bb + (t * 4 + ks) * 512);
                acc[t] = __builtin_amdgcn_mfma_f32_16x16x32_bf16(a[ks], b, acc[t], 0, 0, 0);
            }
        }
        int row0 = blockIdx.x * 128 + strip * 64 + wave * 16 + quad * 4;
#pragma unroll
        for (int t = 0; t < 8; t++) {
            int c = t * 16 + r16;              // packed col 0..127
#pragma unroll
            for (int g = 0; g < 4; g++) {
                int gr = row0 + g;
                if (gr < n) {
                    unsigned int pv = ((unsigned int)f2bf(acc[t + 8][g]) << 16) | f2bf(acc[t][g]);
                    hbp[(size_t)gr * 128 + c] = pv;
                }
            }
        }
        // ---- fused es/ed epilogue ----
        // slot s (0..15): s<8 -> es[row*8+s], s>=8 -> ed[row*8+s-8];
        // es/ed slot = head*2+layer. Reduce-scatter over the 16 r16-lanes:
        // after 4 xor steps, lane r16 holds the full sum for slot r16.
#pragma unroll
        for (int g = 0; g < 4; g++) {
            int grow = row0 + g;
            float v[16];
#pragma unroll
            for (int h = 0; h < 4; h++) {
                float x1 = acc[2 * h][g],     y1 = acc[2 * h + 1][g];      // layer1
                float x2 = acc[8 + 2 * h][g], y2 = acc[8 + 2 * h + 1][g];  // layer2
                v[h * 2 + 0]     = x1 * aS1[h].x + y1 * aS1[h].y;
                v[h * 2 + 1]     = x2 * aS2[h].x + y2 * aS2[h].y;
                v[8 + h * 2 + 0] = x1 * aD1[h].x + y1 * aD1[h].y;
                v[8 + h * 2 + 1] = x2 * aD2[h].x + y2 * aD2[h].y;
            }
            int b0 = r16 & 1, b1 = r16 & 2, b2 = r16 & 4, b3 = r16 & 8;
            float w8[8];
#pragma unroll
            for (int k2 = 0; k2 < 8; k2++) {
                float keep = b0 ? v[2 * k2 + 1] : v[2 * k2];
                float send = b0 ? v[2 * k2]     : v[2 * k2 + 1];
                w8[k2] = keep + __shfl_xor(send, 1, 64);
            }
            float w4v[4];
#pragma unroll
            for (int k2 = 0; k2 < 4; k2++) {
                float keep = b1 ? w8[2 * k2 + 1] : w8[2 * k2];
                float send = b1 ? w8[2 * k2]     : w8[2 * k2 + 1];
                w4v[k2] = keep + __shfl_xor(send, 2, 64);
            }
            float w2v[2];
#pragma unroll
            for (int k2 = 0; k2 < 2; k2++) {
                float keep = b2 ? w4v[2 * k2 + 1] : w4v[2 * k2];
                float send = b2 ? w4v[2 * k2]     : w4v[2 * k2 + 1];
                w2v[k2] = keep + __shfl_xor(send, 4, 64);
            }
            float keep = b3 ? w2v[1] : w2v[0];
            float send = b3 ? w2v[0] : w2v[1];
            float wv = keep + __shfl_xor(send, 8, 64);
            if (grow < n) {
                float* dstp = (r16 < 8) ? (es + (size_t)grow * 8 + r16)
                                        : (ed + (size_t)grow * 8 + (r16 - 8));
                *dstp = wv;
            }
        }
    }
}

// K3: atomic-free counting-sort placement (1024 edges/block).
__global__ void k_fl(const int* __restrict__ ei, const int* __restrict__ cursor8,
                     const unsigned int* __restrict__ pk,
                     int* __restrict__ ssrc, int E, int n) {
#pragma unroll
    for (int it = 0; it < 4; it++) {
        int i = blockIdx.x * 1024 + it * 256 + threadIdx.x;
        if (i < E) {
            int s = ei[i];
            unsigned int v = pk[i];
            int d = (int)(v & 0x1FFFFu);
            int r = (int)(v >> 17);
            int sh = (i >> 8) & (SH - 1);
            ssrc[cursor8[sh * n + d] + r] = s;
        }
    }
}

__device__ __forceinline__ float wred(float v) {
#pragma unroll
    for (int off = 32; off; off >>= 1) v += __shfl_xor(v, off, 64);
    return v;
}

// one wave per node; lane owns packed cols ca=2*lane, cb=2*lane+1 (same head).
// Edge weights recomputed in-register: w = exp(lrelu(es[src]+ed[dst])).
__global__ __launch_bounds__(256) void k_agg(
    const int* __restrict__ offs, const int* __restrict__ ssrc,
    const unsigned int* __restrict__ hbp,
    const float* __restrict__ es, const float* __restrict__ ed,
    const float* __restrict__ b1, const float* __restrict__ b2,
    const float* __restrict__ gW, const float* __restrict__ gb,
    const float* __restrict__ x, const float* __restrict__ gamma,
    const float* __restrict__ beta, float* __restrict__ out, int n) {
    int wave = threadIdx.x >> 6, lane = threadIdx.x & 63;
    int node = blockIdx.x * 4 + wave;
    if (node >= n) return;
    node = __builtin_amdgcn_readfirstlane(node);   // wave-uniform -> s_loads

    int ca = lane * 2;
    int head = lane >> 4;                  // = ca>>5
    int hh = head * 2;                     // slot base in es/ed rows

    float2 edv = *(const float2*)(ed + node * 8 + hh);
    float ed1 = edv.x, ed2 = edv.y;        // dst logit terms, loop-invariant

    float l1 = 0.f, l2 = 0.f;
    float a1a = 0.f, a1b = 0.f, a2a = 0.f, a2b = 0.f;

#define EDGE(sv, q) { \
        float e1 = sv.x + ed1; e1 = fmaxf(e1, LRELU_SLOPE * e1); \
        float e2 = sv.y + ed2; e2 = fmaxf(e2, LRELU_SLOPE * e2); \
        float ww1 = __expf(e1), ww2 = __expf(e2); \
        l1 += ww1; l2 += ww2; \
        a1a += ww1 * bflo(q.x); a1b += ww1 * bflo(q.y); \
        a2a += ww2 * bfhi(q.x); a2b += ww2 * bfhi(q.y); }

    // self-loop (es/ed rows of this node, coalesced hbp row read)
    {
        float2 svs = *(const float2*)(es + node * 8 + hh);
        uint2 qs = *(const uint2*)(hbp + (size_t)node * 128 + ca);
        EDGE(svs, qs)
    }

    int beg = offs[node], end = offs[node + 1];
    int k = beg;
    for (; k + 3 < end; k += 4) {
        int j0 = ssrc[k], j1 = ssrc[k + 1], j2 = ssrc[k + 2], j3 = ssrc[k + 3];
        float2 s0 = *(const float2*)(es + j0 * 8 + hh);
        float2 s1 = *(const float2*)(es + j1 * 8 + hh);
        float2 s2 = *(const float2*)(es + j2 * 8 + hh);
        float2 s3 = *(const float2*)(es + j3 * 8 + hh);
        uint2 q0 = *(const uint2*)(hbp + (size_t)j0 * 128 + ca);
        uint2 q1 = *(const uint2*)(hbp + (size_t)j1 * 128 + ca);
        uint2 q2 = *(const uint2*)(hbp + (size_t)j2 * 128 + ca);
        uint2 q3 = *(const uint2*)(hbp + (size_t)j3 * 128 + ca);
        EDGE(s0, q0) EDGE(s1, q1) EDGE(s2, q2) EDGE(s3, q3)
    }
    for (; k < end; k++) {
        int j = ssrc[k];
        float2 sv = *(const float2*)(es + j * 8 + hh);
        uint2 q = *(const uint2*)(hbp + (size_t)j * 128 + ca);
        EDGE(sv, q)
    }
#undef EDGE

    float2 b1v = *(const float2*)(b1 + ca);
    float2 b2v = *(const float2*)(b2 + ca);
    float r1 = 1.f / l1, r2 = 1.f / l2;
    float o1a = a1a * r1 + b1v.x;
    float o1b = a1b * r1 + b1v.y;
    float o2a = a2a * r2 + b2v.x;
    float o2b = a2b * r2 + b2v.y;

    // gate logits: concat(out1,out2) @ gate_W(256x2) + gate_b
    int cb = ca + 1;
    float2 g1a = *(const float2*)(gW + 2 * ca);          // rows ca,cb
    float2 g1b = *(const float2*)(gW + 2 * cb);
    float2 g2a = *(const float2*)(gW + 2 * (128 + ca));
    float2 g2b = *(const float2*)(gW + 2 * (128 + cb));
    float p0 = o1a * g1a.x + o1b * g1b.x + o2a * g2a.x + o2b * g2b.x;
    float p1 = o1a * g1a.y + o1b * g1b.y + o2a * g2a.y + o2b * g2b.y;
    p0 = wred(p0) + gb[0];
    p1 = wred(p1) + gb[1];
    float mg = fmaxf(p0, p1);
    float eg0 = __expf(p0 - mg), eg1 = __expf(p1 - mg);
    float g0 = eg0 / (eg0 + eg1), g1 = 1.f - g0;

    float2 xv = *(const float2*)(x + (size_t)node * 128 + ca);
    float ya = xv.x + g0 * o1a + g1 * o2a;
    float yb = xv.y + g0 * o1b + g1 * o2b;

    float s  = wred(ya + yb);
    float ss = wred(ya * ya + yb * yb);
    float mean = s * (1.f / 128.f);
    float var  = ss * (1.f / 128.f) - mean * mean;
    float rstd = rsqrtf(var + LN_EPS);
    float2 gv = *(const float2*)(gamma + ca);
    float2 bv = *(const float2*)(beta + ca);
    union { float2 f2; double d; } ov;
    ov.f2.x = (ya - mean) * rstd * gv.x + bv.x;
    ov.f2.y = (yb - mean) * rstd * gv.y + bv.y;
    // nontemporal: out is never re-read; keep L2 for hbp/es gathers
    __builtin_nontemporal_store(ov.d, (double*)(out + (size_t)node * 128 + ca));
}

extern "C" void kernel_launch(void* const* d_in, const int* in_sizes, int n_in,
                              void* d_out, int out_size, void* d_ws, size_t ws_size,
                              hipStream_t stream) {
    const float* x   = (const float*)d_in[0];
    const int*   ei  = (const int*)d_in[1];
    const float* W1  = (const float*)d_in[2];
    const float* b1  = (const float*)d_in[3];
    const float* as1 = (const float*)d_in[4];
    const float* ad1 = (const float*)d_in[5];
    const float* W2  = (const float*)d_in[6];
    const float* b2  = (const float*)d_in[7];
    const float* as2 = (const float*)d_in[8];
    const float* ad2 = (const float*)d_in[9];
    const float* gW  = (const float*)d_in[10];
    const float* gb  = (const float*)d_in[11];
    const float* gamma = (const float*)d_in[12];
    const float* beta  = (const float*)d_in[13];
    float* out = (float*)d_out;

    int n = in_sizes[0] / 128;
    int E = in_sizes[1] / 2;

    char* p = (char*)d_ws;
    auto take = [&](size_t bytes) {
        char* q = p;
        p += (bytes + 255) & ~(size_t)255;
        return (void*)q;
    };
    u16* wb    = (u16*)take((size_t)256 * 128 * 2);
    unsigned int* hbp = (unsigned int*)take((size_t)n * 128 * 4);
    float* es  = (float*)take((size_t)n * 8 * 4);
    float* ed  = (float*)take((size_t)n * 8 * 4);
    int* deg8  = (int*)take((size_t)SH * n * 4);   // becomes slice-start cursors in k_cg scan
    int* offs  = (int*)take((size_t)(n + 1) * 4);
    int* bsum  = (int*)take((size_t)256 * 4);
    int* gflag = (int*)take((size_t)256 * 4);
    int* ssrc  = (int*)take((size_t)E * 4);
    unsigned int* pk = (unsigned int*)take((size_t)E * 4);

    int nb  = (n + 255) / 256;      // 196 (<= 256 required by scan)
    int Gg  = (n + 127) / 128;      // gemm blocks (128 rows each)
    int Gc8 = (E + 2047) / 2048;    // count blocks (2048 edges each)
    int Gso = (E + 1023) / 1024;    // sort blocks (1024 edges each)

    hipMemsetAsync(deg8, 0, (size_t)SH * n * 4, stream);
    k_pc<<<128 + Gc8, 256, 0, stream>>>(W1, W2, wb, deg8, gflag, ei, pk, E, n);
    k_cg<<<Gg + nb, 256, 0, stream>>>(x, wb, hbp, n, as1, ad1, as2, ad2,
                                      es, ed, deg8, offs, bsum, gflag, nb, Gg);
    k_fl<<<Gso, 256, 0, stream>>>(ei, deg8, pk, ssrc, E, n);
    k_agg<<<(n + 3) / 4, 256, 0, stream>>>(offs, ssrc, hbp, es, ed,
                                           b1, b2, gW, gb, x, gamma, beta, out, n);
}